// Round 4
// baseline (178.356 us; speedup 1.0000x reference)
//
#include <hip/hip_runtime.h>

// Native clang vector type — accepted by __builtin_nontemporal_{load,store}.
typedef float f4 __attribute__((ext_vector_type(4)));

// Single-dispatch fused kernel, compute-once-per-ray via intra-wave LDS share.
//
// Wave layout (64 lanes): 16 rays per wave.
//   - lanes 0..15: each computes ONE ray's inverse transform [T|u]
//     (T = R^T, u = -R^T t; 12 floats) and publishes it to LDS.
//   - all 64 lanes: lane l owns output row c = l&3 of ray l>>4... (see below)
//     reads its ray's [T|u] from LDS (broadcast within 4-lane groups) and its
//     own e0 row (16 B; the ray's 4 lanes cover one 64 B line), computes
//     m = e_row · [T|u], stores one float4 — consecutive lanes store
//     consecutive float4s → full-line coalesced nontemporal stream,
//     identical geometry to the 56 µs two-kernel gather.
//
// Math (faithful to reference): vec2skew stacks columns → K = skew(v)^T;
// n = |r|+1e-15; A = sin(n)/n; B = (1-cos(n))/n^2; R = I + A*K + B*K^2 with
// K^2 = r r^T - |r|^2 I; inv(c2w) = [[R^T, -R^T t],[0,0,0,1]];
// out = E0[cam] @ inv(c2w).
__global__ __launch_bounds__(256) void fused_wave_kernel(
        const float* __restrict__ r,
        const float* __restrict__ t,
        const float* __restrict__ e0,
        const int* __restrict__ cid,
        f4* __restrict__ out, int nr) {
    // 4 waves/block, 16 rays/wave, 12 floats of shared state per ray (pad 13).
    __shared__ float Tsh[4][16][13];

    const int lane  = threadIdx.x & 63;
    const int waveb = threadIdx.x >> 6;                     // wave in block
    // First ray of this wave (16 rays per wave, 64 rows per wave).
    const int waveRayBase = (blockIdx.x * 256 + (threadIdx.x & ~63)) >> 2;

    // ---- compute phase: lanes 0..15 handle one ray each ----
    if (lane < 16) {
        const int cray = waveRayBase + lane;
        if (cray < nr) {
            const int f = cid[cray];
            const float rx = r[3 * f + 0], ry = r[3 * f + 1], rz = r[3 * f + 2];
            const float tx = t[3 * f + 0], ty = t[3 * f + 1], tz = t[3 * f + 2];

            const float s = rx * rx + ry * ry + rz * rz;
            const float n = sqrtf(s) + 1e-15f;
            const float sn = sinf(n), cn = cosf(n);
            const float A = sn / n;
            const float B = (1.0f - cn) / (n * n);

            // R = I + A*K + B*(r r^T - s I),  K = skew(r)^T
            const float R00 = 1.0f + B * (rx * rx - s);
            const float R01 =  A * rz + B * (rx * ry);
            const float R02 = -A * ry + B * (rx * rz);
            const float R10 = -A * rz + B * (rx * ry);
            const float R11 = 1.0f + B * (ry * ry - s);
            const float R12 =  A * rx + B * (ry * rz);
            const float R20 =  A * ry + B * (rx * rz);
            const float R21 = -A * rx + B * (ry * rz);
            const float R22 = 1.0f + B * (rz * rz - s);

            // T = R^T (row-major in LDS), u = -R^T t
            float* q = Tsh[waveb][lane];
            q[0] = R00; q[1] = R10; q[2] = R20;   // T row 0
            q[3] = R01; q[4] = R11; q[5] = R21;   // T row 1
            q[6] = R02; q[7] = R12; q[8] = R22;   // T row 2
            q[9]  = -(R00 * tx + R10 * ty + R20 * tz);
            q[10] = -(R01 * tx + R11 * ty + R21 * tz);
            q[11] = -(R02 * tx + R12 * ty + R22 * tz);
        }
    }

    __syncthreads();   // publish LDS (no early returns above — guards only)

    // ---- output phase: every lane stores one float4 row ----
    const int ray = waveRayBase + (lane >> 2);
    if (ray < nr) {
        const int c = lane & 3;
        const int f = cid[ray];                  // L1-hot (same 64 B as above)
        const float* q = Tsh[waveb][lane >> 2];

        // This lane's E0 row: 16 B; ray's 4 lanes cover one 64 B line.
        const f4 e = *reinterpret_cast<const f4*>(e0 + 16 * f + 4 * c);

        f4 m;
        m.x = e.x * q[0] + e.y * q[3] + e.z * q[6];
        m.y = e.x * q[1] + e.y * q[4] + e.z * q[7];
        m.z = e.x * q[2] + e.y * q[5] + e.z * q[8];
        m.w = e.x * q[9] + e.y * q[10] + e.z * q[11] + e.w;

        __builtin_nontemporal_store(m, out + (size_t)ray * 4 + c);
    }
}

extern "C" void kernel_launch(void* const* d_in, const int* in_sizes, int n_in,
                              void* d_out, int out_size, void* d_ws, size_t ws_size,
                              hipStream_t stream) {
    const float* r  = (const float*)d_in[0];   // (NF, 3)
    const float* t  = (const float*)d_in[1];   // (NF, 3)
    const float* e0 = (const float*)d_in[2];   // (NF, 4, 4)
    const int*  cid = (const int*)d_in[3];     // (NR,)
    float* out = (float*)d_out;                // (NR, 4, 4)

    const int nr = in_sizes[3];
    const long long n4 = (long long)nr * 4;    // one thread per output row
    const int threads = 256;
    const int blocks = (int)((n4 + threads - 1) / threads);
    fused_wave_kernel<<<blocks, threads, 0, stream>>>(
        r, t, e0, cid, (f4*)out, nr);
}

// Round 5
// 158.368 us; speedup vs baseline: 1.1262x; 1.1262x over previous
//
#include <hip/hip_runtime.h>

// Native clang vector type (usable with nontemporal builtins if needed).
typedef float f4 __attribute__((ext_vector_type(4)));

// Two-phase structure (best measured: 157.2 µs):
//   1) build_table_kernel: sequential-access per-frame compute, ~3 µs.
//   2) gather_kernel: one thread per output row; all random access is a
//      single 16 B L2-resident table read per lane.
//
// Round-5 change: COMPACT table. M[f] = E0[f] @ inv(c2w_f) always has bottom
// row exactly [0,0,0,1] (both factors do), so store only rows 0..2:
// 48 B/frame -> 480 KB table. Gather lane c==3 writes the constant row with
// no load. 25% less random-read traffic + smaller L2 footprint.
//
// Math (faithful to reference): vec2skew stacks columns -> K = skew(v)^T;
// n = |r|+1e-15; A = sin(n)/n; B = (1-cos(n))/n^2; R = I + A*K + B*K^2,
// K^2 = r r^T - |r|^2 I; inv(c2w) = [[R^T, -R^T t],[0,0,0,1]].
__global__ void build_table_kernel(const float* __restrict__ r,
                                   const float* __restrict__ t,
                                   const float* __restrict__ e0,
                                   float* __restrict__ M, int nf) {
    int f = blockIdx.x * blockDim.x + threadIdx.x;
    if (f >= nf) return;

    const float rx = r[3 * f + 0], ry = r[3 * f + 1], rz = r[3 * f + 2];
    const float tx = t[3 * f + 0], ty = t[3 * f + 1], tz = t[3 * f + 2];

    const float s = rx * rx + ry * ry + rz * rz;
    const float n = sqrtf(s) + 1e-15f;
    const float sn = sinf(n), cn = cosf(n);
    const float A = sn / n;
    const float B = (1.0f - cn) / (n * n);

    // R = I + A*K + B*(r r^T - s I),  K = [[0,rz,-ry],[-rz,0,rx],[ry,-rx,0]]
    const float R00 = 1.0f + B * (rx * rx - s);
    const float R01 =  A * rz + B * (rx * ry);
    const float R02 = -A * ry + B * (rx * rz);
    const float R10 = -A * rz + B * (rx * ry);
    const float R11 = 1.0f + B * (ry * ry - s);
    const float R12 =  A * rx + B * (ry * rz);
    const float R20 =  A * ry + B * (rx * rz);
    const float R21 = -A * rx + B * (ry * rz);
    const float R22 = 1.0f + B * (rz * rz - s);

    // T = R^T, u = -R^T t
    const float T00 = R00, T01 = R10, T02 = R20;
    const float T10 = R01, T11 = R11, T12 = R21;
    const float T20 = R02, T21 = R12, T22 = R22;
    const float u0 = -(T00 * tx + T01 * ty + T02 * tz);
    const float u1 = -(T10 * tx + T11 * ty + T12 * tz);
    const float u2 = -(T20 * tx + T21 * ty + T22 * tz);

    // M rows 0..2 only: row i = (E0_i · T_col0, ·T_col1, ·T_col2, E0_i·u + e3)
    const float* E = e0 + 16 * f;
    f4* Mo = reinterpret_cast<f4*>(M + 12 * f);
    #pragma unroll
    for (int i = 0; i < 3; ++i) {
        const float a0 = E[4 * i + 0], a1 = E[4 * i + 1];
        const float a2 = E[4 * i + 2], a3 = E[4 * i + 3];
        f4 m;
        m.x = a0 * T00 + a1 * T10 + a2 * T20;
        m.y = a0 * T01 + a1 * T11 + a2 * T21;
        m.z = a0 * T02 + a1 * T12 + a2 * T22;
        m.w = a0 * u0 + a1 * u1 + a2 * u2 + a3;
        Mo[i] = m;
    }
}

// One thread per output float4 row. Lanes c=0..2 read 16 B from the compact
// table (48 B/frame, 480 KB total, L2-resident); lane c=3 stores the constant
// bottom row with no load. Stores: consecutive lanes -> consecutive float4s,
// fully coalesced (regular caching stores — the best-measured config).
__global__ __launch_bounds__(256) void gather_kernel(
        const int* __restrict__ cid,
        const f4* __restrict__ M,   // 3 rows per frame
        f4* __restrict__ out, int n4) {
    const int tid = blockIdx.x * blockDim.x + threadIdx.x;
    if (tid >= n4) return;
    const int ray = tid >> 2;
    const int c   = tid & 3;
    f4 m = {0.0f, 0.0f, 0.0f, 1.0f};
    if (c < 3) {
        const int cam = cid[ray];
        m = M[cam * 3 + c];
    }
    out[tid] = m;
}

// Fallback (ws too small): fused per-ray compute (correct, slower).
__global__ void fused_kernel(const float* __restrict__ r,
                             const float* __restrict__ t,
                             const float* __restrict__ e0,
                             const int* __restrict__ cid,
                             f4* __restrict__ out, int nr) {
    int ray = blockIdx.x * blockDim.x + threadIdx.x;
    if (ray >= nr) return;
    const int f = cid[ray];

    const float rx = r[3 * f + 0], ry = r[3 * f + 1], rz = r[3 * f + 2];
    const float tx = t[3 * f + 0], ty = t[3 * f + 1], tz = t[3 * f + 2];
    const float s = rx * rx + ry * ry + rz * rz;
    const float n = sqrtf(s) + 1e-15f;
    const float sn = sinf(n), cn = cosf(n);
    const float A = sn / n;
    const float B = (1.0f - cn) / (n * n);
    const float R00 = 1.0f + B * (rx * rx - s);
    const float R01 =  A * rz + B * (rx * ry);
    const float R02 = -A * ry + B * (rx * rz);
    const float R10 = -A * rz + B * (rx * ry);
    const float R11 = 1.0f + B * (ry * ry - s);
    const float R12 =  A * rx + B * (ry * rz);
    const float R20 =  A * ry + B * (rx * rz);
    const float R21 = -A * rx + B * (ry * rz);
    const float R22 = 1.0f + B * (rz * rz - s);
    const float T00 = R00, T01 = R10, T02 = R20;
    const float T10 = R01, T11 = R11, T12 = R21;
    const float T20 = R02, T21 = R12, T22 = R22;
    const float u0 = -(T00 * tx + T01 * ty + T02 * tz);
    const float u1 = -(T10 * tx + T11 * ty + T12 * tz);
    const float u2 = -(T20 * tx + T21 * ty + T22 * tz);

    const float* E = e0 + 16 * f;
    #pragma unroll
    for (int i = 0; i < 4; ++i) {
        const float a0 = E[4 * i + 0], a1 = E[4 * i + 1];
        const float a2 = E[4 * i + 2], a3 = E[4 * i + 3];
        f4 m;
        m.x = a0 * T00 + a1 * T10 + a2 * T20;
        m.y = a0 * T01 + a1 * T11 + a2 * T21;
        m.z = a0 * T02 + a1 * T12 + a2 * T22;
        m.w = a0 * u0 + a1 * u1 + a2 * u2 + a3;
        out[(size_t)ray * 4 + i] = m;
    }
}

extern "C" void kernel_launch(void* const* d_in, const int* in_sizes, int n_in,
                              void* d_out, int out_size, void* d_ws, size_t ws_size,
                              hipStream_t stream) {
    const float* r  = (const float*)d_in[0];   // (NF, 3)
    const float* t  = (const float*)d_in[1];   // (NF, 3)
    const float* e0 = (const float*)d_in[2];   // (NF, 4, 4)
    const int*  cid = (const int*)d_in[3];     // (NR,)
    float* out = (float*)d_out;                // (NR, 4, 4)

    const int nf = in_sizes[0] / 3;
    const int nr = in_sizes[3];
    const size_t table_bytes = (size_t)nf * 12 * sizeof(float);  // compact

    if (ws_size >= table_bytes) {
        float* M = (float*)d_ws;
        {
            int threads = 256;
            int blocks = (nf + threads - 1) / threads;
            build_table_kernel<<<blocks, threads, 0, stream>>>(r, t, e0, M, nf);
        }
        {
            const int n4 = nr * 4;   // one thread per output float4 row
            int threads = 256;
            int blocks = (n4 + threads - 1) / threads;
            gather_kernel<<<blocks, threads, 0, stream>>>(
                cid, (const f4*)M, (f4*)out, n4);
        }
    } else {
        int threads = 256;
        int blocks = (nr + threads - 1) / threads;
        fused_kernel<<<blocks, threads, 0, stream>>>(
            r, t, e0, cid, (f4*)out, nr);
    }
}